// Round 6
// baseline (530.248 us; speedup 1.0000x reference)
//
#include <hip/hip_runtime.h>
#include <math.h>

// GatedPrototypeDistillationLoss, MI355X gfx950 — round 6.
//  * [granule][row] LDS layout for A and B tiles -> fragment ds_read_b128 are
//    lane-contiguous 16B (conflict-free). P' is pre-transposed in ws by
//    kprep_p so B staging is linear on BOTH global and LDS sides.
//    (round-2..5 layout had a structural 4-way bank conflict: row = 4 granules
//     = 64B, half the 128B bank period; 2-bit XOR can't spread 32 lanes.)
//  * krescore2: wave-parallel coalesced rescore (was per-lane row scans).
//  * pipeline/top-2/digest logic identical to round 5.

#define NB 32768
#define ND 512
#define NK 2048
#define TEMPR 0.07f
#define INV_T 14.285714285714286f
#define DX 1.4285714e-4f  // near-tie margin in x-domain (=1e-5 sim / T)

typedef unsigned short u16;
using bf16x8 = __attribute__((ext_vector_type(8))) short;
using u16x8 = __attribute__((ext_vector_type(8))) unsigned short;
using f32x16 = __attribute__((ext_vector_type(16))) float;

__device__ inline u16 bf_hi(float x) {  // fp32 -> bf16 bits, RNE
  unsigned u = __float_as_uint(x);
  u = u + 0x7FFFu + ((u >> 16) & 1u);
  return (u16)(u >> 16);
}
__device__ inline float bf_tof(u16 h) {
  return __uint_as_float(((unsigned)h) << 16);
}
__device__ inline void gload_lds16(const void* g, void* l) {
  __builtin_amdgcn_global_load_lds((const __attribute__((address_space(1))) void*)g,
                                   (__attribute__((address_space(3))) void*)l, 16, 0, 0);
}
#define MF(a, b, c) __builtin_amdgcn_mfma_f32_32x32x16_bf16((a), (b), (c), 0, 0, 0)

#define WAIT_LGKM0 { asm volatile("s_waitcnt lgkmcnt(0)" ::: "memory"); \
                     __builtin_amdgcn_sched_barrier(0); }
#define WAIT_VM10  { asm volatile("s_waitcnt vmcnt(10)" ::: "memory"); \
                     __builtin_amdgcn_sched_barrier(0); }
#define SBAR       { __builtin_amdgcn_s_barrier(); \
                     __builtin_amdgcn_sched_barrier(0); }

// ---- kernel 1: P -> normalized bf16 hi/lo, TRANSPOSED tile layout ----------
// Phi_t/Plo_t u16 layout: [kt(8)][dt(16)][g(4)][proto(256)][8]
//   (tile (kt,dt) = 1024 slots of 16B; slot = g*256 + local_proto)
__global__ __launch_bounds__(256) void kprep_p(const float* __restrict__ P,
                                               u16* __restrict__ Phi,
                                               u16* __restrict__ Plo,
                                               int* __restrict__ cnt) {
  if (blockIdx.x == 0 && threadIdx.x == 0) *cnt = 0;
  const int lane = threadIdx.x & 63, w = threadIdx.x >> 6;
  const int p = blockIdx.x * 4 + w;  // grid 512 -> 2048 rows
  const float4* pr = (const float4*)(P + (size_t)p * ND);
  float4 a = pr[2 * lane], b = pr[2 * lane + 1];  // granule `lane`: d=8*lane..+7
  float ss = a.x * a.x + a.y * a.y + a.z * a.z + a.w * a.w
           + b.x * b.x + b.y * b.y + b.z * b.z + b.w * b.w;
#pragma unroll
  for (int off = 32; off > 0; off >>= 1) ss += __shfl_xor(ss, off);
  const float inv = 1.0f / fmaxf(sqrtf(ss), 1e-12f);
  u16x8 h8, l8;
#define PCNV(j, f) { float n_ = (f) * inv; u16 hb_ = bf_hi(n_); \
  h8[j] = hb_; l8[j] = bf_hi(n_ - bf_tof(hb_)); }
  PCNV(0, a.x) PCNV(1, a.y) PCNV(2, a.z) PCNV(3, a.w)
  PCNV(4, b.x) PCNV(5, b.y) PCNV(6, b.z) PCNV(7, b.w)
#undef PCNV
  const int kt = p >> 8, pl = p & 255;
  const size_t idx = ((size_t)((kt * 16 + (lane >> 2)) * 4 + (lane & 3)) * 256 + pl) * 8;
  *(u16x8*)(Phi + idx) = h8;
  *(u16x8*)(Plo + idx) = l8;
}

// ---------------- kernel 2: E -> normalized bf16 hi/lo (row-major) ----------
__global__ __launch_bounds__(256) void kprep_e2(const float* __restrict__ E,
                                                u16* __restrict__ Ehi,
                                                u16* __restrict__ Elo) {
  const int lane = threadIdx.x & 63, w = threadIdx.x >> 6;
  const int row = blockIdx.x * 4 + w;  // grid 8192 -> 32768 rows
  const float4* er = (const float4*)(E + (size_t)row * ND);
  float4 a = er[lane], b = er[lane + 64];
  float ss = a.x * a.x + a.y * a.y + a.z * a.z + a.w * a.w
           + b.x * b.x + b.y * b.y + b.z * b.z + b.w * b.w;
#pragma unroll
  for (int off = 32; off > 0; off >>= 1) ss += __shfl_xor(ss, off);
  const float inv = 1.0f / fmaxf(sqrtf(ss), 1e-12f);
  ushort4 h4, l4;
#define PCNV(dst_h, dst_l, f) { float n_ = (f) * inv; u16 hb_ = bf_hi(n_); \
  dst_h = hb_; dst_l = bf_hi(n_ - bf_tof(hb_)); }
  PCNV(h4.x, l4.x, a.x) PCNV(h4.y, l4.y, a.y) PCNV(h4.z, l4.z, a.z) PCNV(h4.w, l4.w, a.w)
  *(ushort4*)(Ehi + (size_t)row * ND + lane * 4) = h4;
  *(ushort4*)(Elo + (size_t)row * ND + lane * 4) = l4;
  PCNV(h4.x, l4.x, b.x) PCNV(h4.y, l4.y, b.y) PCNV(h4.z, l4.z, b.z) PCNV(h4.w, l4.w, b.w)
  *(ushort4*)(Ehi + (size_t)row * ND + (lane + 64) * 4) = h4;
  *(ushort4*)(Elo + (size_t)row * ND + (lane + 64) * 4) = l4;
#undef PCNV
}

// online update with exact top-2 tracking (x-domain logit, fixed offset)
#define UPD2(r, vv, pp) { \
  float x_ = fmaf((vv), INV_T, -INV_T); \
  float e_ = __expf(x_); \
  sS[r] += e_; uS[r] = fmaf(x_, e_, uS[r]); \
  bool u1_ = x_ > m1[r]; \
  float lo_ = u1_ ? m1[r] : x_; \
  m2[r] = fmaxf(m2[r], lo_); \
  m1[r] = u1_ ? x_ : m1[r]; \
  ix[r] = u1_ ? (pp) : ix[r]; }

// ====== kernel 3: MFMA GEMM, [granule][row] LDS, counted-vmcnt pipeline =====
__global__ __launch_bounds__(256, 2) void kmain_v6(
    const float* __restrict__ BS,
    const u16* __restrict__ PhiG, const u16* __restrict__ PloG,
    const u16* __restrict__ EhiG, const u16* __restrict__ EloG,
    const float* __restrict__ CONF,
    float* __restrict__ tau_ws, float* __restrict__ gd, float* __restrict__ gate_out,
    int* __restrict__ cnt, int* __restrict__ flags) {
  // LDS u16 layouts: A [g(4)][row(64)][8] ; B [g(4)][proto(256)][8]
  __shared__ u16 Ahi[2][2048], Alo[2][2048];
  __shared__ u16 Bhi[2][8192], Blo[2][8192];

  const int t = threadIdx.x;
  const int lane = t & 63;
  const int w = t >> 6, wr = w >> 1, wc = w & 1;
  const int c = lane & 31, h = lane >> 5;
  const int swz = (blockIdx.x & 7) * 64 + (blockIdx.x >> 3);  // XCD swizzle (512=8*64)
  const int row0 = swz * 64;

  // A staging: thread t -> LDS slot t = (g=w)*64 + (row=lane); source strided
  const u16* EhiA = EhiG + (size_t)(row0 + lane) * ND + w * 8;
  const u16* EloA = EloG + (size_t)(row0 + lane) * ND + w * 8;

  // B staging: 4 instr/wave; slot index doubles as src offset (pre-transposed)
  int boff[4];
#pragma unroll
  for (int i = 0; i < 4; ++i) boff[i] = (w * 256 + i * 64 + lane) * 8;

  // fragment-read offsets (u16 units), lane-contiguous 16B -> conflict-free
  const int ao0 = ((h)*64 + wr * 32 + c) * 8;        // ks=0 granule h
  const int ao1 = ((2 + h) * 64 + wr * 32 + c) * 8;  // ks=1 granule 2+h
  const int bo0 = ((h)*256 + wc * 128 + c) * 8;
  const int bo1 = ((2 + h) * 256 + wc * 128 + c) * 8;

  f32x16 acc0, acc1, acc2, acc3;
#pragma unroll
  for (int i = 0; i < 16; ++i) { acc0[i] = 0.f; acc1[i] = 0.f; acc2[i] = 0.f; acc3[i] = 0.f; }
  float sS[16], uS[16], m1[16], m2[16];
  int ix[16];
#pragma unroll
  for (int r = 0; r < 16; ++r) {
    sS[r] = 0.f; uS[r] = 0.f; m1[r] = -3.0e38f; m2[r] = -3.0e38f; ix[r] = 0;
  }

#define SB6(tile_u16, nx) { \
  _Pragma("unroll") \
  for (int i = 0; i < 4; ++i) { \
    gload_lds16(PhiG + (tile_u16) + boff[i], &Bhi[nx][boff[i]]); \
    gload_lds16(PloG + (tile_u16) + boff[i], &Blo[nx][boff[i]]); \
  } }
#define SA6(col, nx) { \
  gload_lds16(EhiA + (col), &Ahi[nx][t * 8]); \
  gload_lds16(EloA + (col), &Alo[nx][t * 8]); }

  // prologue: stage step 0 -> buf0, step 1 -> buf1; wait step0 only
  SB6(0, 0);
  SA6(0, 0);
  SB6(8192, 1);
  SA6(32, 1);
  WAIT_VM10;
  SBAR;

#pragma unroll 2
  for (int step = 0; step < 128; ++step) {
    const int cur = step & 1;
    // ---- phase R: all 20 fragment reads from buf[cur] ----
    const bf16x8 eh0 = *(const bf16x8*)&Ahi[cur][ao0];
    const bf16x8 el0 = *(const bf16x8*)&Alo[cur][ao0];
    const bf16x8 eh1 = *(const bf16x8*)&Ahi[cur][ao1];
    const bf16x8 el1 = *(const bf16x8*)&Alo[cur][ao1];
    const bf16x8 bh00 = *(const bf16x8*)&Bhi[cur][bo0];
    const bf16x8 bh01 = *(const bf16x8*)&Bhi[cur][bo0 + 256];
    const bf16x8 bh02 = *(const bf16x8*)&Bhi[cur][bo0 + 512];
    const bf16x8 bh03 = *(const bf16x8*)&Bhi[cur][bo0 + 768];
    const bf16x8 bl00 = *(const bf16x8*)&Blo[cur][bo0];
    const bf16x8 bl01 = *(const bf16x8*)&Blo[cur][bo0 + 256];
    const bf16x8 bl02 = *(const bf16x8*)&Blo[cur][bo0 + 512];
    const bf16x8 bl03 = *(const bf16x8*)&Blo[cur][bo0 + 768];
    const bf16x8 bh10 = *(const bf16x8*)&Bhi[cur][bo1];
    const bf16x8 bh11 = *(const bf16x8*)&Bhi[cur][bo1 + 256];
    const bf16x8 bh12 = *(const bf16x8*)&Bhi[cur][bo1 + 512];
    const bf16x8 bh13 = *(const bf16x8*)&Bhi[cur][bo1 + 768];
    const bf16x8 bl10 = *(const bf16x8*)&Blo[cur][bo1];
    const bf16x8 bl11 = *(const bf16x8*)&Blo[cur][bo1 + 256];
    const bf16x8 bl12 = *(const bf16x8*)&Blo[cur][bo1 + 512];
    const bf16x8 bl13 = *(const bf16x8*)&Blo[cur][bo1 + 768];

    // ---- MFMA ks=0 ----
    acc0 = MF(eh0, bh00, acc0); acc1 = MF(eh0, bh01, acc1);
    acc2 = MF(eh0, bh02, acc2); acc3 = MF(eh0, bh03, acc3);
    acc0 = MF(eh0, bl00, acc0); acc1 = MF(eh0, bl01, acc1);
    acc2 = MF(eh0, bl02, acc2); acc3 = MF(eh0, bl03, acc3);
    acc0 = MF(el0, bh00, acc0); acc1 = MF(el0, bh01, acc1);
    acc2 = MF(el0, bh02, acc2); acc3 = MF(el0, bh03, acc3);

    // ---- barrier 1: all waves done READING buf[cur]; no vmcnt drain ----
    WAIT_LGKM0;
    SBAR;

    // ---- phase S: stage step+2 into buf[cur] ----
    const int ns = (step < 126) ? step + 2 : 127;  // tail dup, never read
    SB6(ns * 8192, cur);
    SA6((ns & 15) * 32, cur);

    // ---- MFMA ks=1 ----
    acc0 = MF(eh1, bh10, acc0); acc1 = MF(eh1, bh11, acc1);
    acc2 = MF(eh1, bh12, acc2); acc3 = MF(eh1, bh13, acc3);
    acc0 = MF(eh1, bl10, acc0); acc1 = MF(eh1, bl11, acc1);
    acc2 = MF(eh1, bl12, acc2); acc3 = MF(eh1, bl13, acc3);
    acc0 = MF(el1, bh10, acc0); acc1 = MF(el1, bh11, acc1);
    acc2 = MF(el1, bh12, acc2); acc3 = MF(el1, bh13, acc3);

    if ((step & 15) == 15) {  // kt-tile digest (overlaps in-flight stages)
      const int pidb = (step >> 4) * 256 + wc * 128 + c;
#pragma unroll
      for (int r = 0; r < 16; ++r) {
        UPD2(r, acc0[r], pidb)
        UPD2(r, acc1[r], pidb + 32)
        UPD2(r, acc2[r], pidb + 64)
        UPD2(r, acc3[r], pidb + 96)
        acc0[r] = 0.f; acc1[r] = 0.f; acc2[r] = 0.f; acc3[r] = 0.f;
      }
    }

    // ---- barrier 2: retire ONLY step t+1's 10 loads (counted vmcnt) ----
    WAIT_VM10;
    SBAR;
  }

  __syncthreads();  // full drain (tail dup-stages still write Ahi/Bhi)

  // ---- butterfly merge across the 32 proto-partition lanes ----
#pragma unroll
  for (int off = 1; off < 32; off <<= 1) {
#pragma unroll
    for (int r = 0; r < 16; ++r) {
      float m1o = __shfl_xor(m1[r], off);
      float m2o = __shfl_xor(m2[r], off);
      float so = __shfl_xor(sS[r], off);
      float uo = __shfl_xor(uS[r], off);
      int io = __shfl_xor(ix[r], off);
      sS[r] += so; uS[r] += uo;
      bool up = (m1o > m1[r]) || (m1o == m1[r] && io < ix[r]);
      float losr = (m1o > m1[r]) ? m1[r] : m1o;  // min(m1, m1o)
      m2[r] = fmaxf(fmaxf(m2[r], m2o), losr);
      m1[r] = fmaxf(m1[r], m1o);
      ix[r] = up ? io : ix[r];
    }
  }

  // ---- cross-wave (wc) merge via LDS (alias onto Ahi, compute done) ----
  float* mg = (float*)&Ahi[0][0];  // [wr][wc][32 rows][6]
  if (c == 0) {
#pragma unroll
    for (int r = 0; r < 16; ++r) {
      int rowl = (r & 3) + 8 * (r >> 2) + 4 * h;
      int base = ((wr * 2 + wc) * 32 + rowl) * 6;
      mg[base + 0] = m1[r];
      mg[base + 1] = sS[r];
      mg[base + 2] = uS[r];
      mg[base + 3] = __int_as_float(ix[r]);
      mg[base + 4] = m2[r];
    }
  }
  __syncthreads();

  if ((w & 1) == 0 && lane < 32) {
    const int rowl = lane;
    const int b0 = ((wr * 2 + 0) * 32 + rowl) * 6;
    const int b1 = ((wr * 2 + 1) * 32 + rowl) * 6;
    float m1a = mg[b0], s0 = mg[b0 + 1], u0 = mg[b0 + 2];
    int i0 = __float_as_int(mg[b0 + 3]);
    float m2a = mg[b0 + 4];
    float m1b = mg[b1], s1 = mg[b1 + 1], u1 = mg[b1 + 2];
    int i1 = __float_as_int(mg[b1 + 3]);
    float m2b = mg[b1 + 4];

    bool up = (m1b > m1a) || (m1b == m1a && i1 < i0);
    float m = fmaxf(m1a, m1b);
    float m2f = fmaxf(fmaxf(m2a, m2b), fminf(m1a, m1b));
    int idx = up ? i1 : i0;
    bool flg = (m - m2f) < DX;  // exact: final top-2 gap below margin
    float s = s0 + s1, u = u0 + u1;

    float ent = logf(s) - u / s;  // = lse - E[logit]
    float tau = 0.5f - 0.2f * (ent * (1.0f / (7.6246190071f + 1e-8f)));
    float simmax = fmaf(m, TEMPR, 1.0f);  // m is (sim-1)/T
    float dist = sqrtf(fmaxf(2.0f - 2.0f * simmax, 0.0f));
    int grow = row0 + wr * 32 + rowl;
    float g = CONF[idx] / (1.0f + __expf(-(BS[grow] - tau) * INV_T));
    gate_out[grow] = g;
    gd[grow] = g * dist;
    tau_ws[grow] = tau;
    if (flg) {
      int p = atomicAdd(cnt, 1);
      flags[p] = grow;
    }
  }
}

// ------- kernel 4: fp32 rescore of near-tie rows (wave-parallel, coalesced) -
__global__ __launch_bounds__(256) void krescore2(
    const float* __restrict__ E, const float* __restrict__ P,
    const float* __restrict__ BS, const float* __restrict__ CONF,
    const float* __restrict__ tau_ws, const int* __restrict__ cnt,
    const int* __restrict__ flags, float* __restrict__ gd,
    float* __restrict__ gate_out) {
  __shared__ float en[512];
  __shared__ float red[256];
  __shared__ float wbest[4];
  __shared__ int widx[4];
  __shared__ float sinv_s;
  const int n = *cnt;
  const int t = threadIdx.x;
  const int w = t >> 6, lane = t & 63;
  for (int j = blockIdx.x; j < n; j += gridDim.x) {
    const int row = flags[j];
    float2 v = ((const float2*)(E + (size_t)row * ND))[t];
    red[t] = v.x * v.x + v.y * v.y;
    __syncthreads();
    for (int o = 128; o > 0; o >>= 1) {
      if (t < o) red[t] += red[t + o];
      __syncthreads();
    }
    if (t == 0) sinv_s = 1.0f / fmaxf(sqrtf(red[0]), 1e-12f);
    __syncthreads();
    const float sinv = sinv_s;
    en[2 * t] = v.x * sinv;
    en[2 * t + 1] = v.y * sinv;
    __syncthreads();

    const float4 e0 = ((const float4*)en)[2 * lane];
    const float4 e1 = ((const float4*)en)[2 * lane + 1];
    float best = -3.0e38f;
    int bidx = NK;
    for (int p = w; p < NK; p += 4) {  // ascending within wave: first-max kept
      const float4* pr = (const float4*)(P + (size_t)p * ND);
      float4 a = pr[2 * lane], b = pr[2 * lane + 1];
      float dot = 0.f, pp = 0.f;
      dot = fmaf(a.x, e0.x, dot); dot = fmaf(a.y, e0.y, dot);
      dot = fmaf(a.z, e0.z, dot); dot = fmaf(a.w, e0.w, dot);
      dot = fmaf(b.x, e1.x, dot); dot = fmaf(b.y, e1.y, dot);
      dot = fmaf(b.z, e1.z, dot); dot = fmaf(b.w, e1.w, dot);
      pp = fmaf(a.x, a.x, pp); pp = fmaf(a.y, a.y, pp);
      pp = fmaf(a.z, a.z, pp); pp = fmaf(a.w, a.w, pp);
      pp = fmaf(b.x, b.x, pp); pp = fmaf(b.y, b.y, pp);
      pp = fmaf(b.z, b.z, pp); pp = fmaf(b.w, b.w, pp);
#pragma unroll
      for (int o = 32; o > 0; o >>= 1) {
        dot += __shfl_xor(dot, o);
        pp += __shfl_xor(pp, o);
      }
      float sim = dot / fmaxf(sqrtf(pp), 1e-12f);
      if (sim > best) { best = sim; bidx = p; }
    }
    if (lane == 0) { wbest[w] = best; widx[w] = bidx; }
    __syncthreads();
    if (t == 0) {
      float bb = wbest[0];
      int bi = widx[0];
#pragma unroll
      for (int i = 1; i < 4; ++i) {
        float vv = wbest[i];
        int ii = widx[i];
        if (vv > bb || (vv == bb && ii < bi)) { bb = vv; bi = ii; }
      }
      float tau = tau_ws[row];
      float dist = sqrtf(fmaxf(2.0f - 2.0f * bb, 0.0f));
      float g = CONF[bi] / (1.0f + __expf(-(BS[row] - tau) * INV_T));
      gate_out[row] = g;
      gd[row] = g * dist;
    }
    __syncthreads();
  }
}

// ---------------- kernel 5: deterministic mean ----------------
__global__ __launch_bounds__(1024) void kreduce(const float* __restrict__ gd,
                                                float* __restrict__ out0) {
  __shared__ float red[1024];
  const int t = threadIdx.x;
  float s = 0.f;
  const float4* g4 = (const float4*)gd;
  for (int i = t; i < 8192; i += 1024) {
    float4 v = g4[i];
    s += (v.x + v.y) + (v.z + v.w);
  }
  red[t] = s;
  __syncthreads();
  for (int off = 512; off > 0; off >>= 1) {
    if (t < off) red[t] += red[t + off];
    __syncthreads();
  }
  if (t == 0) out0[0] = red[0] * (1.0f / 32768.0f);
}

extern "C" void kernel_launch(void* const* d_in, const int* in_sizes, int n_in,
                              void* d_out, int out_size, void* d_ws, size_t ws_size,
                              hipStream_t stream) {
  const float* E = (const float*)d_in[0];
  const float* BS = (const float*)d_in[1];
  const float* P = (const float*)d_in[2];
  const float* CONF = (const float*)d_in[3];
  float* out = (float*)d_out;  // [0]=L_proto, [1..32768]=gate

  char* wsb = (char*)d_ws;
  u16* Phi = (u16*)wsb;                                   // 2 MB @ 0 (transposed)
  u16* Plo = (u16*)(wsb + ((size_t)2 << 20));             // 2 MB @ 2M (transposed)
  u16* Ehi = (u16*)(wsb + ((size_t)4 << 20));             // 32 MB @ 4M (row-major)
  u16* Elo = (u16*)(wsb + ((size_t)36 << 20));            // 32 MB @ 36M
  float* tau_ws = (float*)(wsb + ((size_t)68 << 20));     // 128 KB
  float* gd = (float*)(wsb + ((size_t)68 << 20) + 131072);
  int* flags = (int*)(wsb + ((size_t)68 << 20) + 2 * 131072);
  int* cnt = (int*)(wsb + ((size_t)68 << 20) + 3 * 131072);

  kprep_p<<<512, 256, 0, stream>>>(P, Phi, Plo, cnt);
  kprep_e2<<<8192, 256, 0, stream>>>(E, Ehi, Elo);
  kmain_v6<<<512, 256, 0, stream>>>(BS, Phi, Plo, Ehi, Elo, CONF, tau_ws, gd,
                                    out + 1, cnt, flags);
  krescore2<<<64, 256, 0, stream>>>(E, P, BS, CONF, tau_ws, cnt, flags, gd, out + 1);
  kreduce<<<1, 1024, 0, stream>>>(gd, out);
}

// Round 7
// 412.840 us; speedup vs baseline: 1.2844x; 1.2844x over previous
//
#include <hip/hip_runtime.h>
#include <math.h>

// GatedPrototypeDistillationLoss, MI355X gfx950 — round 7.
//  * krescore3: one block per flagged row; 16-lane groups own protos;
//    E-chunk in registers (group-shfl norm), coalesced P reads, group-tree
//    reduce. Replaces round-6's latency-bound per-proto wave reduce (292 us)
//    and round-5's uncoalesced per-thread scan (~130 us).
//  * kprep_p additionally stores inv_p (fp32) for the rescore.
//  * kmain_v6 ([granule][row] conflict-free LDS + counted-vmcnt) unchanged.

#define NB 32768
#define ND 512
#define NK 2048
#define TEMPR 0.07f
#define INV_T 14.285714285714286f
#define DX 1.4285714e-4f  // near-tie margin in x-domain (=1e-5 sim / T)

typedef unsigned short u16;
using bf16x8 = __attribute__((ext_vector_type(8))) short;
using u16x8 = __attribute__((ext_vector_type(8))) unsigned short;
using f32x16 = __attribute__((ext_vector_type(16))) float;

__device__ inline u16 bf_hi(float x) {  // fp32 -> bf16 bits, RNE
  unsigned u = __float_as_uint(x);
  u = u + 0x7FFFu + ((u >> 16) & 1u);
  return (u16)(u >> 16);
}
__device__ inline float bf_tof(u16 h) {
  return __uint_as_float(((unsigned)h) << 16);
}
__device__ inline void gload_lds16(const void* g, void* l) {
  __builtin_amdgcn_global_load_lds((const __attribute__((address_space(1))) void*)g,
                                   (__attribute__((address_space(3))) void*)l, 16, 0, 0);
}
#define MF(a, b, c) __builtin_amdgcn_mfma_f32_32x32x16_bf16((a), (b), (c), 0, 0, 0)

#define WAIT_LGKM0 { asm volatile("s_waitcnt lgkmcnt(0)" ::: "memory"); \
                     __builtin_amdgcn_sched_barrier(0); }
#define WAIT_VM10  { asm volatile("s_waitcnt vmcnt(10)" ::: "memory"); \
                     __builtin_amdgcn_sched_barrier(0); }
#define SBAR       { __builtin_amdgcn_s_barrier(); \
                     __builtin_amdgcn_sched_barrier(0); }

// ---- kernel 1: P -> normalized bf16 hi/lo (transposed tiles) + inv_p -------
// Phi/Plo u16 layout: [kt(8)][dt(16)][g(4)][proto(256)][8]
__global__ __launch_bounds__(256) void kprep_p(const float* __restrict__ P,
                                               u16* __restrict__ Phi,
                                               u16* __restrict__ Plo,
                                               float* __restrict__ invp,
                                               int* __restrict__ cnt) {
  if (blockIdx.x == 0 && threadIdx.x == 0) *cnt = 0;
  const int lane = threadIdx.x & 63, w = threadIdx.x >> 6;
  const int p = blockIdx.x * 4 + w;  // grid 512 -> 2048 rows
  const float4* pr = (const float4*)(P + (size_t)p * ND);
  float4 a = pr[2 * lane], b = pr[2 * lane + 1];  // granule `lane`: d=8*lane..+7
  float ss = a.x * a.x + a.y * a.y + a.z * a.z + a.w * a.w
           + b.x * b.x + b.y * b.y + b.z * b.z + b.w * b.w;
#pragma unroll
  for (int off = 32; off > 0; off >>= 1) ss += __shfl_xor(ss, off);
  const float inv = 1.0f / fmaxf(sqrtf(ss), 1e-12f);
  if (lane == 0) invp[p] = inv;
  u16x8 h8, l8;
#define PCNV(j, f) { float n_ = (f) * inv; u16 hb_ = bf_hi(n_); \
  h8[j] = hb_; l8[j] = bf_hi(n_ - bf_tof(hb_)); }
  PCNV(0, a.x) PCNV(1, a.y) PCNV(2, a.z) PCNV(3, a.w)
  PCNV(4, b.x) PCNV(5, b.y) PCNV(6, b.z) PCNV(7, b.w)
#undef PCNV
  const int kt = p >> 8, pl = p & 255;
  const size_t idx = ((size_t)((kt * 16 + (lane >> 2)) * 4 + (lane & 3)) * 256 + pl) * 8;
  *(u16x8*)(Phi + idx) = h8;
  *(u16x8*)(Plo + idx) = l8;
}

// ---------------- kernel 2: E -> normalized bf16 hi/lo (row-major) ----------
__global__ __launch_bounds__(256) void kprep_e2(const float* __restrict__ E,
                                                u16* __restrict__ Ehi,
                                                u16* __restrict__ Elo) {
  const int lane = threadIdx.x & 63, w = threadIdx.x >> 6;
  const int row = blockIdx.x * 4 + w;  // grid 8192 -> 32768 rows
  const float4* er = (const float4*)(E + (size_t)row * ND);
  float4 a = er[lane], b = er[lane + 64];
  float ss = a.x * a.x + a.y * a.y + a.z * a.z + a.w * a.w
           + b.x * b.x + b.y * b.y + b.z * b.z + b.w * b.w;
#pragma unroll
  for (int off = 32; off > 0; off >>= 1) ss += __shfl_xor(ss, off);
  const float inv = 1.0f / fmaxf(sqrtf(ss), 1e-12f);
  ushort4 h4, l4;
#define PCNV(dst_h, dst_l, f) { float n_ = (f) * inv; u16 hb_ = bf_hi(n_); \
  dst_h = hb_; dst_l = bf_hi(n_ - bf_tof(hb_)); }
  PCNV(h4.x, l4.x, a.x) PCNV(h4.y, l4.y, a.y) PCNV(h4.z, l4.z, a.z) PCNV(h4.w, l4.w, a.w)
  *(ushort4*)(Ehi + (size_t)row * ND + lane * 4) = h4;
  *(ushort4*)(Elo + (size_t)row * ND + lane * 4) = l4;
  PCNV(h4.x, l4.x, b.x) PCNV(h4.y, l4.y, b.y) PCNV(h4.z, l4.z, b.z) PCNV(h4.w, l4.w, b.w)
  *(ushort4*)(Ehi + (size_t)row * ND + (lane + 64) * 4) = h4;
  *(ushort4*)(Elo + (size_t)row * ND + (lane + 64) * 4) = l4;
#undef PCNV
}

// online update with exact top-2 tracking (x-domain logit, fixed offset)
#define UPD2(r, vv, pp) { \
  float x_ = fmaf((vv), INV_T, -INV_T); \
  float e_ = __expf(x_); \
  sS[r] += e_; uS[r] = fmaf(x_, e_, uS[r]); \
  bool u1_ = x_ > m1[r]; \
  float lo_ = u1_ ? m1[r] : x_; \
  m2[r] = fmaxf(m2[r], lo_); \
  m1[r] = u1_ ? x_ : m1[r]; \
  ix[r] = u1_ ? (pp) : ix[r]; }

// ====== kernel 3: MFMA GEMM, [granule][row] LDS, counted-vmcnt pipeline =====
__global__ __launch_bounds__(256, 2) void kmain_v6(
    const float* __restrict__ BS,
    const u16* __restrict__ PhiG, const u16* __restrict__ PloG,
    const u16* __restrict__ EhiG, const u16* __restrict__ EloG,
    const float* __restrict__ CONF,
    float* __restrict__ tau_ws, float* __restrict__ gd, float* __restrict__ gate_out,
    int* __restrict__ cnt, int* __restrict__ flags) {
  // LDS u16 layouts: A [g(4)][row(64)][8] ; B [g(4)][proto(256)][8]
  __shared__ u16 Ahi[2][2048], Alo[2][2048];
  __shared__ u16 Bhi[2][8192], Blo[2][8192];

  const int t = threadIdx.x;
  const int lane = t & 63;
  const int w = t >> 6, wr = w >> 1, wc = w & 1;
  const int c = lane & 31, h = lane >> 5;
  const int swz = (blockIdx.x & 7) * 64 + (blockIdx.x >> 3);  // XCD swizzle (512=8*64)
  const int row0 = swz * 64;

  // A staging: thread t -> LDS slot t = (g=w)*64 + (row=lane); source strided
  const u16* EhiA = EhiG + (size_t)(row0 + lane) * ND + w * 8;
  const u16* EloA = EloG + (size_t)(row0 + lane) * ND + w * 8;

  // B staging: 4 instr/wave; slot index doubles as src offset (pre-transposed)
  int boff[4];
#pragma unroll
  for (int i = 0; i < 4; ++i) boff[i] = (w * 256 + i * 64 + lane) * 8;

  // fragment-read offsets (u16 units), lane-contiguous 16B -> conflict-free
  const int ao0 = ((h)*64 + wr * 32 + c) * 8;        // ks=0 granule h
  const int ao1 = ((2 + h) * 64 + wr * 32 + c) * 8;  // ks=1 granule 2+h
  const int bo0 = ((h)*256 + wc * 128 + c) * 8;
  const int bo1 = ((2 + h) * 256 + wc * 128 + c) * 8;

  f32x16 acc0, acc1, acc2, acc3;
#pragma unroll
  for (int i = 0; i < 16; ++i) { acc0[i] = 0.f; acc1[i] = 0.f; acc2[i] = 0.f; acc3[i] = 0.f; }
  float sS[16], uS[16], m1[16], m2[16];
  int ix[16];
#pragma unroll
  for (int r = 0; r < 16; ++r) {
    sS[r] = 0.f; uS[r] = 0.f; m1[r] = -3.0e38f; m2[r] = -3.0e38f; ix[r] = 0;
  }

#define SB6(tile_u16, nx) { \
  _Pragma("unroll") \
  for (int i = 0; i < 4; ++i) { \
    gload_lds16(PhiG + (tile_u16) + boff[i], &Bhi[nx][boff[i]]); \
    gload_lds16(PloG + (tile_u16) + boff[i], &Blo[nx][boff[i]]); \
  } }
#define SA6(col, nx) { \
  gload_lds16(EhiA + (col), &Ahi[nx][t * 8]); \
  gload_lds16(EloA + (col), &Alo[nx][t * 8]); }

  // prologue: stage step 0 -> buf0, step 1 -> buf1; wait step0 only
  SB6(0, 0);
  SA6(0, 0);
  SB6(8192, 1);
  SA6(32, 1);
  WAIT_VM10;
  SBAR;

#pragma unroll 2
  for (int step = 0; step < 128; ++step) {
    const int cur = step & 1;
    // ---- phase R: all 20 fragment reads from buf[cur] ----
    const bf16x8 eh0 = *(const bf16x8*)&Ahi[cur][ao0];
    const bf16x8 el0 = *(const bf16x8*)&Alo[cur][ao0];
    const bf16x8 eh1 = *(const bf16x8*)&Ahi[cur][ao1];
    const bf16x8 el1 = *(const bf16x8*)&Alo[cur][ao1];
    const bf16x8 bh00 = *(const bf16x8*)&Bhi[cur][bo0];
    const bf16x8 bh01 = *(const bf16x8*)&Bhi[cur][bo0 + 256];
    const bf16x8 bh02 = *(const bf16x8*)&Bhi[cur][bo0 + 512];
    const bf16x8 bh03 = *(const bf16x8*)&Bhi[cur][bo0 + 768];
    const bf16x8 bl00 = *(const bf16x8*)&Blo[cur][bo0];
    const bf16x8 bl01 = *(const bf16x8*)&Blo[cur][bo0 + 256];
    const bf16x8 bl02 = *(const bf16x8*)&Blo[cur][bo0 + 512];
    const bf16x8 bl03 = *(const bf16x8*)&Blo[cur][bo0 + 768];
    const bf16x8 bh10 = *(const bf16x8*)&Bhi[cur][bo1];
    const bf16x8 bh11 = *(const bf16x8*)&Bhi[cur][bo1 + 256];
    const bf16x8 bh12 = *(const bf16x8*)&Bhi[cur][bo1 + 512];
    const bf16x8 bh13 = *(const bf16x8*)&Bhi[cur][bo1 + 768];
    const bf16x8 bl10 = *(const bf16x8*)&Blo[cur][bo1];
    const bf16x8 bl11 = *(const bf16x8*)&Blo[cur][bo1 + 256];
    const bf16x8 bl12 = *(const bf16x8*)&Blo[cur][bo1 + 512];
    const bf16x8 bl13 = *(const bf16x8*)&Blo[cur][bo1 + 768];

    // ---- MFMA ks=0 ----
    acc0 = MF(eh0, bh00, acc0); acc1 = MF(eh0, bh01, acc1);
    acc2 = MF(eh0, bh02, acc2); acc3 = MF(eh0, bh03, acc3);
    acc0 = MF(eh0, bl00, acc0); acc1 = MF(eh0, bl01, acc1);
    acc2 = MF(eh0, bl02, acc2); acc3 = MF(eh0, bl03, acc3);
    acc0 = MF(el0, bh00, acc0); acc1 = MF(el0, bh01, acc1);
    acc2 = MF(el0, bh02, acc2); acc3 = MF(el0, bh03, acc3);

    // ---- barrier 1: all waves done READING buf[cur]; no vmcnt drain ----
    WAIT_LGKM0;
    SBAR;

    // ---- phase S: stage step+2 into buf[cur] ----
    const int ns = (step < 126) ? step + 2 : 127;  // tail dup, never read
    SB6(ns * 8192, cur);
    SA6((ns & 15) * 32, cur);

    // ---- MFMA ks=1 ----
    acc0 = MF(eh1, bh10, acc0); acc1 = MF(eh1, bh11, acc1);
    acc2 = MF(eh1, bh12, acc2); acc3 = MF(eh1, bh13, acc3);
    acc0 = MF(eh1, bl10, acc0); acc1 = MF(eh1, bl11, acc1);
    acc2 = MF(eh1, bl12, acc2); acc3 = MF(eh1, bl13, acc3);
    acc0 = MF(el1, bh10, acc0); acc1 = MF(el1, bh11, acc1);
    acc2 = MF(el1, bh12, acc2); acc3 = MF(el1, bh13, acc3);

    if ((step & 15) == 15) {  // kt-tile digest (overlaps in-flight stages)
      const int pidb = (step >> 4) * 256 + wc * 128 + c;
#pragma unroll
      for (int r = 0; r < 16; ++r) {
        UPD2(r, acc0[r], pidb)
        UPD2(r, acc1[r], pidb + 32)
        UPD2(r, acc2[r], pidb + 64)
        UPD2(r, acc3[r], pidb + 96)
        acc0[r] = 0.f; acc1[r] = 0.f; acc2[r] = 0.f; acc3[r] = 0.f;
      }
    }

    // ---- barrier 2: retire ONLY step t+1's 10 loads (counted vmcnt) ----
    WAIT_VM10;
    SBAR;
  }

  __syncthreads();  // full drain (tail dup-stages still write Ahi/Bhi)

  // ---- butterfly merge across the 32 proto-partition lanes ----
#pragma unroll
  for (int off = 1; off < 32; off <<= 1) {
#pragma unroll
    for (int r = 0; r < 16; ++r) {
      float m1o = __shfl_xor(m1[r], off);
      float m2o = __shfl_xor(m2[r], off);
      float so = __shfl_xor(sS[r], off);
      float uo = __shfl_xor(uS[r], off);
      int io = __shfl_xor(ix[r], off);
      sS[r] += so; uS[r] += uo;
      bool up = (m1o > m1[r]) || (m1o == m1[r] && io < ix[r]);
      float losr = (m1o > m1[r]) ? m1[r] : m1o;  // min(m1, m1o)
      m2[r] = fmaxf(fmaxf(m2[r], m2o), losr);
      m1[r] = fmaxf(m1[r], m1o);
      ix[r] = up ? io : ix[r];
    }
  }

  // ---- cross-wave (wc) merge via LDS (alias onto Ahi, compute done) ----
  float* mg = (float*)&Ahi[0][0];  // [wr][wc][32 rows][6]
  if (c == 0) {
#pragma unroll
    for (int r = 0; r < 16; ++r) {
      int rowl = (r & 3) + 8 * (r >> 2) + 4 * h;
      int base = ((wr * 2 + wc) * 32 + rowl) * 6;
      mg[base + 0] = m1[r];
      mg[base + 1] = sS[r];
      mg[base + 2] = uS[r];
      mg[base + 3] = __int_as_float(ix[r]);
      mg[base + 4] = m2[r];
    }
  }
  __syncthreads();

  if ((w & 1) == 0 && lane < 32) {
    const int rowl = lane;
    const int b0 = ((wr * 2 + 0) * 32 + rowl) * 6;
    const int b1 = ((wr * 2 + 1) * 32 + rowl) * 6;
    float m1a = mg[b0], s0 = mg[b0 + 1], u0 = mg[b0 + 2];
    int i0 = __float_as_int(mg[b0 + 3]);
    float m2a = mg[b0 + 4];
    float m1b = mg[b1], s1 = mg[b1 + 1], u1 = mg[b1 + 2];
    int i1 = __float_as_int(mg[b1 + 3]);
    float m2b = mg[b1 + 4];

    bool up = (m1b > m1a) || (m1b == m1a && i1 < i0);
    float m = fmaxf(m1a, m1b);
    float m2f = fmaxf(fmaxf(m2a, m2b), fminf(m1a, m1b));
    int idx = up ? i1 : i0;
    bool flg = (m - m2f) < DX;  // exact: final top-2 gap below margin
    float s = s0 + s1, u = u0 + u1;

    float ent = logf(s) - u / s;  // = lse - E[logit]
    float tau = 0.5f - 0.2f * (ent * (1.0f / (7.6246190071f + 1e-8f)));
    float simmax = fmaf(m, TEMPR, 1.0f);  // m is (sim-1)/T
    float dist = sqrtf(fmaxf(2.0f - 2.0f * simmax, 0.0f));
    int grow = row0 + wr * 32 + rowl;
    float g = CONF[idx] / (1.0f + __expf(-(BS[grow] - tau) * INV_T));
    gate_out[grow] = g;
    gd[grow] = g * dist;
    tau_ws[grow] = tau;
    if (flg) {
      int p = atomicAdd(cnt, 1);
      flags[p] = grow;
    }
  }
}

// --- kernel 4: fp32 rescore (block per row; 16-lane groups; coalesced P) ----
__global__ __launch_bounds__(256) void krescore3(
    const float* __restrict__ E, const float* __restrict__ P,
    const float* __restrict__ BS, const float* __restrict__ CONF,
    const float* __restrict__ tau_ws, const float* __restrict__ invp,
    const int* __restrict__ cnt, const int* __restrict__ flags,
    float* __restrict__ gd, float* __restrict__ gate_out) {
  __shared__ float gb[16];
  __shared__ int gi[16];
  const int n = *cnt;
  const int t = threadIdx.x;
  const int k = t & 15;   // lane in 16-lane group
  const int G = t >> 4;   // group 0..15

  for (int j = blockIdx.x; j < n; j += gridDim.x) {
    const int row = flags[j];
    // E chunk (dims k*4 + 64*i .. +3) in registers; group-shfl norm
    float4 e[8];
    float ss = 0.f;
    const float4* er = (const float4*)(E + (size_t)row * ND);
#pragma unroll
    for (int i = 0; i < 8; ++i) {
      e[i] = er[k + 16 * i];
      ss += e[i].x * e[i].x + e[i].y * e[i].y + e[i].z * e[i].z + e[i].w * e[i].w;
    }
#pragma unroll
    for (int o = 1; o < 16; o <<= 1) ss += __shfl_xor(ss, o);
    const float inv = 1.0f / fmaxf(sqrtf(ss), 1e-12f);
#pragma unroll
    for (int i = 0; i < 8; ++i) {
      e[i].x *= inv; e[i].y *= inv; e[i].z *= inv; e[i].w *= inv;
    }

    float best = -3.0e38f;
    int bidx = NK;
    for (int p = G; p < NK; p += 16) {  // ascending within group: first-max kept
      const float4* pr = (const float4*)(P + (size_t)p * ND);
      float dot = 0.f;
#pragma unroll
      for (int i = 0; i < 8; ++i) {
        float4 a = pr[k + 16 * i];
        dot = fmaf(a.x, e[i].x, dot); dot = fmaf(a.y, e[i].y, dot);
        dot = fmaf(a.z, e[i].z, dot); dot = fmaf(a.w, e[i].w, dot);
      }
#pragma unroll
      for (int o = 1; o < 16; o <<= 1) dot += __shfl_xor(dot, o);
      float sim = dot * invp[p];
      if (sim > best) { best = sim; bidx = p; }
    }
    if (k == 0) { gb[G] = best; gi[G] = bidx; }
    __syncthreads();
    if (t == 0) {
      float bb = gb[0];
      int bi = gi[0];
#pragma unroll
      for (int i = 1; i < 16; ++i) {
        float vv = gb[i];
        int ii = gi[i];
        if (vv > bb || (vv == bb && ii < bi)) { bb = vv; bi = ii; }
      }
      float tau = tau_ws[row];
      float dist = sqrtf(fmaxf(2.0f - 2.0f * bb, 0.0f));
      float g = CONF[bi] / (1.0f + __expf(-(BS[row] - tau) * INV_T));
      gate_out[row] = g;
      gd[row] = g * dist;
    }
    __syncthreads();
  }
}

// ---------------- kernel 5: deterministic mean ----------------
__global__ __launch_bounds__(1024) void kreduce(const float* __restrict__ gd,
                                                float* __restrict__ out0) {
  __shared__ float red[1024];
  const int t = threadIdx.x;
  float s = 0.f;
  const float4* g4 = (const float4*)gd;
  for (int i = t; i < 8192; i += 1024) {
    float4 v = g4[i];
    s += (v.x + v.y) + (v.z + v.w);
  }
  red[t] = s;
  __syncthreads();
  for (int off = 512; off > 0; off >>= 1) {
    if (t < off) red[t] += red[t + off];
    __syncthreads();
  }
  if (t == 0) out0[0] = red[0] * (1.0f / 32768.0f);
}

extern "C" void kernel_launch(void* const* d_in, const int* in_sizes, int n_in,
                              void* d_out, int out_size, void* d_ws, size_t ws_size,
                              hipStream_t stream) {
  const float* E = (const float*)d_in[0];
  const float* BS = (const float*)d_in[1];
  const float* P = (const float*)d_in[2];
  const float* CONF = (const float*)d_in[3];
  float* out = (float*)d_out;  // [0]=L_proto, [1..32768]=gate

  char* wsb = (char*)d_ws;
  u16* Phi = (u16*)wsb;                                   // 2 MB @ 0 (transposed)
  u16* Plo = (u16*)(wsb + ((size_t)2 << 20));             // 2 MB @ 2M (transposed)
  u16* Ehi = (u16*)(wsb + ((size_t)4 << 20));             // 32 MB @ 4M (row-major)
  u16* Elo = (u16*)(wsb + ((size_t)36 << 20));            // 32 MB @ 36M
  float* tau_ws = (float*)(wsb + ((size_t)68 << 20));     // 128 KB
  float* gd = (float*)(wsb + ((size_t)68 << 20) + 131072);
  int* flags = (int*)(wsb + ((size_t)68 << 20) + 2 * 131072);
  int* cnt = (int*)(wsb + ((size_t)68 << 20) + 3 * 131072);
  float* invp = (float*)(wsb + ((size_t)68 << 20) + 3 * 131072 + 4096);

  kprep_p<<<512, 256, 0, stream>>>(P, Phi, Plo, invp, cnt);
  kprep_e2<<<8192, 256, 0, stream>>>(E, Ehi, Elo);
  kmain_v6<<<512, 256, 0, stream>>>(BS, Phi, Plo, Ehi, Elo, CONF, tau_ws, gd,
                                    out + 1, cnt, flags);
  krescore3<<<64, 256, 0, stream>>>(E, P, BS, CONF, tau_ws, invp, cnt, flags,
                                    gd, out + 1);
  kreduce<<<1, 1024, 0, stream>>>(gd, out);
}

// Round 8
// 265.035 us; speedup vs baseline: 2.0007x; 1.5577x over previous
//
#include <hip/hip_runtime.h>
#include <math.h>

// GatedPrototypeDistillationLoss, MI355X gfx950 — round 8.
//  * krescore4: flagged rows split into 16 proto-chunks fanned over 2048
//    blocks (8 serial iters/block instead of 128 — latency hidden by block
//    parallelism). Chunks merge via atomicMax on packed u64
//    (ordered_sim<<32 | NK-idx): order-independent, exact fp32, first-max ties.
//  * kreduce2: fixup phase (unpack pk -> gate/gd for flagged rows) + mean.
//  * kmain_v6 ([granule][row] conflict-free LDS + counted-vmcnt) unchanged
//    except pk[row]=0 init at flag time. Round-7 counters: conflicts 2.1e7->2048.

#define NB 32768
#define ND 512
#define NK 2048
#define TEMPR 0.07f
#define INV_T 14.285714285714286f
#define DX 1.4285714e-4f  // near-tie margin in x-domain (=1e-5 sim / T)

typedef unsigned short u16;
typedef unsigned long long u64;
using bf16x8 = __attribute__((ext_vector_type(8))) short;
using u16x8 = __attribute__((ext_vector_type(8))) unsigned short;
using f32x16 = __attribute__((ext_vector_type(16))) float;

__device__ inline u16 bf_hi(float x) {  // fp32 -> bf16 bits, RNE
  unsigned u = __float_as_uint(x);
  u = u + 0x7FFFu + ((u >> 16) & 1u);
  return (u16)(u >> 16);
}
__device__ inline float bf_tof(u16 h) {
  return __uint_as_float(((unsigned)h) << 16);
}
__device__ inline void gload_lds16(const void* g, void* l) {
  __builtin_amdgcn_global_load_lds((const __attribute__((address_space(1))) void*)g,
                                   (__attribute__((address_space(3))) void*)l, 16, 0, 0);
}
#define MF(a, b, c) __builtin_amdgcn_mfma_f32_32x32x16_bf16((a), (b), (c), 0, 0, 0)

#define WAIT_LGKM0 { asm volatile("s_waitcnt lgkmcnt(0)" ::: "memory"); \
                     __builtin_amdgcn_sched_barrier(0); }
#define WAIT_VM10  { asm volatile("s_waitcnt vmcnt(10)" ::: "memory"); \
                     __builtin_amdgcn_sched_barrier(0); }
#define SBAR       { __builtin_amdgcn_s_barrier(); \
                     __builtin_amdgcn_sched_barrier(0); }

// ---- kernel 1: P -> normalized bf16 hi/lo (transposed tiles) + inv_p -------
// Phi/Plo u16 layout: [kt(8)][dt(16)][g(4)][proto(256)][8]
__global__ __launch_bounds__(256) void kprep_p(const float* __restrict__ P,
                                               u16* __restrict__ Phi,
                                               u16* __restrict__ Plo,
                                               float* __restrict__ invp,
                                               int* __restrict__ cnt) {
  if (blockIdx.x == 0 && threadIdx.x == 0) *cnt = 0;
  const int lane = threadIdx.x & 63, w = threadIdx.x >> 6;
  const int p = blockIdx.x * 4 + w;  // grid 512 -> 2048 rows
  const float4* pr = (const float4*)(P + (size_t)p * ND);
  float4 a = pr[2 * lane], b = pr[2 * lane + 1];  // granule `lane`: d=8*lane..+7
  float ss = a.x * a.x + a.y * a.y + a.z * a.z + a.w * a.w
           + b.x * b.x + b.y * b.y + b.z * b.z + b.w * b.w;
#pragma unroll
  for (int off = 32; off > 0; off >>= 1) ss += __shfl_xor(ss, off);
  const float inv = 1.0f / fmaxf(sqrtf(ss), 1e-12f);
  if (lane == 0) invp[p] = inv;
  u16x8 h8, l8;
#define PCNV(j, f) { float n_ = (f) * inv; u16 hb_ = bf_hi(n_); \
  h8[j] = hb_; l8[j] = bf_hi(n_ - bf_tof(hb_)); }
  PCNV(0, a.x) PCNV(1, a.y) PCNV(2, a.z) PCNV(3, a.w)
  PCNV(4, b.x) PCNV(5, b.y) PCNV(6, b.z) PCNV(7, b.w)
#undef PCNV
  const int kt = p >> 8, pl = p & 255;
  const size_t idx = ((size_t)((kt * 16 + (lane >> 2)) * 4 + (lane & 3)) * 256 + pl) * 8;
  *(u16x8*)(Phi + idx) = h8;
  *(u16x8*)(Plo + idx) = l8;
}

// ---------------- kernel 2: E -> normalized bf16 hi/lo (row-major) ----------
__global__ __launch_bounds__(256) void kprep_e2(const float* __restrict__ E,
                                                u16* __restrict__ Ehi,
                                                u16* __restrict__ Elo) {
  const int lane = threadIdx.x & 63, w = threadIdx.x >> 6;
  const int row = blockIdx.x * 4 + w;  // grid 8192 -> 32768 rows
  const float4* er = (const float4*)(E + (size_t)row * ND);
  float4 a = er[lane], b = er[lane + 64];
  float ss = a.x * a.x + a.y * a.y + a.z * a.z + a.w * a.w
           + b.x * b.x + b.y * b.y + b.z * b.z + b.w * b.w;
#pragma unroll
  for (int off = 32; off > 0; off >>= 1) ss += __shfl_xor(ss, off);
  const float inv = 1.0f / fmaxf(sqrtf(ss), 1e-12f);
  ushort4 h4, l4;
#define PCNV(dst_h, dst_l, f) { float n_ = (f) * inv; u16 hb_ = bf_hi(n_); \
  dst_h = hb_; dst_l = bf_hi(n_ - bf_tof(hb_)); }
  PCNV(h4.x, l4.x, a.x) PCNV(h4.y, l4.y, a.y) PCNV(h4.z, l4.z, a.z) PCNV(h4.w, l4.w, a.w)
  *(ushort4*)(Ehi + (size_t)row * ND + lane * 4) = h4;
  *(ushort4*)(Elo + (size_t)row * ND + lane * 4) = l4;
  PCNV(h4.x, l4.x, b.x) PCNV(h4.y, l4.y, b.y) PCNV(h4.z, l4.z, b.z) PCNV(h4.w, l4.w, b.w)
  *(ushort4*)(Ehi + (size_t)row * ND + (lane + 64) * 4) = h4;
  *(ushort4*)(Elo + (size_t)row * ND + (lane + 64) * 4) = l4;
#undef PCNV
}

// online update with exact top-2 tracking (x-domain logit, fixed offset)
#define UPD2(r, vv, pp) { \
  float x_ = fmaf((vv), INV_T, -INV_T); \
  float e_ = __expf(x_); \
  sS[r] += e_; uS[r] = fmaf(x_, e_, uS[r]); \
  bool u1_ = x_ > m1[r]; \
  float lo_ = u1_ ? m1[r] : x_; \
  m2[r] = fmaxf(m2[r], lo_); \
  m1[r] = u1_ ? x_ : m1[r]; \
  ix[r] = u1_ ? (pp) : ix[r]; }

// ====== kernel 3: MFMA GEMM, [granule][row] LDS, counted-vmcnt pipeline =====
__global__ __launch_bounds__(256, 2) void kmain_v6(
    const float* __restrict__ BS,
    const u16* __restrict__ PhiG, const u16* __restrict__ PloG,
    const u16* __restrict__ EhiG, const u16* __restrict__ EloG,
    const float* __restrict__ CONF,
    float* __restrict__ tau_ws, float* __restrict__ gd, float* __restrict__ gate_out,
    int* __restrict__ cnt, int* __restrict__ flags, u64* __restrict__ pk) {
  // LDS u16 layouts: A [g(4)][row(64)][8] ; B [g(4)][proto(256)][8]
  __shared__ u16 Ahi[2][2048], Alo[2][2048];
  __shared__ u16 Bhi[2][8192], Blo[2][8192];

  const int t = threadIdx.x;
  const int lane = t & 63;
  const int w = t >> 6, wr = w >> 1, wc = w & 1;
  const int c = lane & 31, h = lane >> 5;
  const int swz = (blockIdx.x & 7) * 64 + (blockIdx.x >> 3);  // XCD swizzle (512=8*64)
  const int row0 = swz * 64;

  // A staging: thread t -> LDS slot t = (g=w)*64 + (row=lane); source strided
  const u16* EhiA = EhiG + (size_t)(row0 + lane) * ND + w * 8;
  const u16* EloA = EloG + (size_t)(row0 + lane) * ND + w * 8;

  // B staging: 4 instr/wave; slot index doubles as src offset (pre-transposed)
  int boff[4];
#pragma unroll
  for (int i = 0; i < 4; ++i) boff[i] = (w * 256 + i * 64 + lane) * 8;

  // fragment-read offsets (u16 units), lane-contiguous 16B -> conflict-free
  const int ao0 = ((h)*64 + wr * 32 + c) * 8;        // ks=0 granule h
  const int ao1 = ((2 + h) * 64 + wr * 32 + c) * 8;  // ks=1 granule 2+h
  const int bo0 = ((h)*256 + wc * 128 + c) * 8;
  const int bo1 = ((2 + h) * 256 + wc * 128 + c) * 8;

  f32x16 acc0, acc1, acc2, acc3;
#pragma unroll
  for (int i = 0; i < 16; ++i) { acc0[i] = 0.f; acc1[i] = 0.f; acc2[i] = 0.f; acc3[i] = 0.f; }
  float sS[16], uS[16], m1[16], m2[16];
  int ix[16];
#pragma unroll
  for (int r = 0; r < 16; ++r) {
    sS[r] = 0.f; uS[r] = 0.f; m1[r] = -3.0e38f; m2[r] = -3.0e38f; ix[r] = 0;
  }

#define SB6(tile_u16, nx) { \
  _Pragma("unroll") \
  for (int i = 0; i < 4; ++i) { \
    gload_lds16(PhiG + (tile_u16) + boff[i], &Bhi[nx][boff[i]]); \
    gload_lds16(PloG + (tile_u16) + boff[i], &Blo[nx][boff[i]]); \
  } }
#define SA6(col, nx) { \
  gload_lds16(EhiA + (col), &Ahi[nx][t * 8]); \
  gload_lds16(EloA + (col), &Alo[nx][t * 8]); }

  // prologue: stage step 0 -> buf0, step 1 -> buf1; wait step0 only
  SB6(0, 0);
  SA6(0, 0);
  SB6(8192, 1);
  SA6(32, 1);
  WAIT_VM10;
  SBAR;

#pragma unroll 2
  for (int step = 0; step < 128; ++step) {
    const int cur = step & 1;
    // ---- phase R: all 20 fragment reads from buf[cur] ----
    const bf16x8 eh0 = *(const bf16x8*)&Ahi[cur][ao0];
    const bf16x8 el0 = *(const bf16x8*)&Alo[cur][ao0];
    const bf16x8 eh1 = *(const bf16x8*)&Ahi[cur][ao1];
    const bf16x8 el1 = *(const bf16x8*)&Alo[cur][ao1];
    const bf16x8 bh00 = *(const bf16x8*)&Bhi[cur][bo0];
    const bf16x8 bh01 = *(const bf16x8*)&Bhi[cur][bo0 + 256];
    const bf16x8 bh02 = *(const bf16x8*)&Bhi[cur][bo0 + 512];
    const bf16x8 bh03 = *(const bf16x8*)&Bhi[cur][bo0 + 768];
    const bf16x8 bl00 = *(const bf16x8*)&Blo[cur][bo0];
    const bf16x8 bl01 = *(const bf16x8*)&Blo[cur][bo0 + 256];
    const bf16x8 bl02 = *(const bf16x8*)&Blo[cur][bo0 + 512];
    const bf16x8 bl03 = *(const bf16x8*)&Blo[cur][bo0 + 768];
    const bf16x8 bh10 = *(const bf16x8*)&Bhi[cur][bo1];
    const bf16x8 bh11 = *(const bf16x8*)&Bhi[cur][bo1 + 256];
    const bf16x8 bh12 = *(const bf16x8*)&Bhi[cur][bo1 + 512];
    const bf16x8 bh13 = *(const bf16x8*)&Bhi[cur][bo1 + 768];
    const bf16x8 bl10 = *(const bf16x8*)&Blo[cur][bo1];
    const bf16x8 bl11 = *(const bf16x8*)&Blo[cur][bo1 + 256];
    const bf16x8 bl12 = *(const bf16x8*)&Blo[cur][bo1 + 512];
    const bf16x8 bl13 = *(const bf16x8*)&Blo[cur][bo1 + 768];

    // ---- MFMA ks=0 ----
    acc0 = MF(eh0, bh00, acc0); acc1 = MF(eh0, bh01, acc1);
    acc2 = MF(eh0, bh02, acc2); acc3 = MF(eh0, bh03, acc3);
    acc0 = MF(eh0, bl00, acc0); acc1 = MF(eh0, bl01, acc1);
    acc2 = MF(eh0, bl02, acc2); acc3 = MF(eh0, bl03, acc3);
    acc0 = MF(el0, bh00, acc0); acc1 = MF(el0, bh01, acc1);
    acc2 = MF(el0, bh02, acc2); acc3 = MF(el0, bh03, acc3);

    // ---- barrier 1: all waves done READING buf[cur]; no vmcnt drain ----
    WAIT_LGKM0;
    SBAR;

    // ---- phase S: stage step+2 into buf[cur] ----
    const int ns = (step < 126) ? step + 2 : 127;  // tail dup, never read
    SB6(ns * 8192, cur);
    SA6((ns & 15) * 32, cur);

    // ---- MFMA ks=1 ----
    acc0 = MF(eh1, bh10, acc0); acc1 = MF(eh1, bh11, acc1);
    acc2 = MF(eh1, bh12, acc2); acc3 = MF(eh1, bh13, acc3);
    acc0 = MF(eh1, bl10, acc0); acc1 = MF(eh1, bl11, acc1);
    acc2 = MF(eh1, bl12, acc2); acc3 = MF(eh1, bl13, acc3);
    acc0 = MF(el1, bh10, acc0); acc1 = MF(el1, bh11, acc1);
    acc2 = MF(el1, bh12, acc2); acc3 = MF(el1, bh13, acc3);

    if ((step & 15) == 15) {  // kt-tile digest (overlaps in-flight stages)
      const int pidb = (step >> 4) * 256 + wc * 128 + c;
#pragma unroll
      for (int r = 0; r < 16; ++r) {
        UPD2(r, acc0[r], pidb)
        UPD2(r, acc1[r], pidb + 32)
        UPD2(r, acc2[r], pidb + 64)
        UPD2(r, acc3[r], pidb + 96)
        acc0[r] = 0.f; acc1[r] = 0.f; acc2[r] = 0.f; acc3[r] = 0.f;
      }
    }

    // ---- barrier 2: retire ONLY step t+1's 10 loads (counted vmcnt) ----
    WAIT_VM10;
    SBAR;
  }

  __syncthreads();  // full drain (tail dup-stages still write Ahi/Bhi)

  // ---- butterfly merge across the 32 proto-partition lanes ----
#pragma unroll
  for (int off = 1; off < 32; off <<= 1) {
#pragma unroll
    for (int r = 0; r < 16; ++r) {
      float m1o = __shfl_xor(m1[r], off);
      float m2o = __shfl_xor(m2[r], off);
      float so = __shfl_xor(sS[r], off);
      float uo = __shfl_xor(uS[r], off);
      int io = __shfl_xor(ix[r], off);
      sS[r] += so; uS[r] += uo;
      bool up = (m1o > m1[r]) || (m1o == m1[r] && io < ix[r]);
      float losr = (m1o > m1[r]) ? m1[r] : m1o;  // min(m1, m1o)
      m2[r] = fmaxf(fmaxf(m2[r], m2o), losr);
      m1[r] = fmaxf(m1[r], m1o);
      ix[r] = up ? io : ix[r];
    }
  }

  // ---- cross-wave (wc) merge via LDS (alias onto Ahi, compute done) ----
  float* mg = (float*)&Ahi[0][0];  // [wr][wc][32 rows][6]
  if (c == 0) {
#pragma unroll
    for (int r = 0; r < 16; ++r) {
      int rowl = (r & 3) + 8 * (r >> 2) + 4 * h;
      int base = ((wr * 2 + wc) * 32 + rowl) * 6;
      mg[base + 0] = m1[r];
      mg[base + 1] = sS[r];
      mg[base + 2] = uS[r];
      mg[base + 3] = __int_as_float(ix[r]);
      mg[base + 4] = m2[r];
    }
  }
  __syncthreads();

  if ((w & 1) == 0 && lane < 32) {
    const int rowl = lane;
    const int b0 = ((wr * 2 + 0) * 32 + rowl) * 6;
    const int b1 = ((wr * 2 + 1) * 32 + rowl) * 6;
    float m1a = mg[b0], s0 = mg[b0 + 1], u0 = mg[b0 + 2];
    int i0 = __float_as_int(mg[b0 + 3]);
    float m2a = mg[b0 + 4];
    float m1b = mg[b1], s1 = mg[b1 + 1], u1 = mg[b1 + 2];
    int i1 = __float_as_int(mg[b1 + 3]);
    float m2b = mg[b1 + 4];

    bool up = (m1b > m1a) || (m1b == m1a && i1 < i0);
    float m = fmaxf(m1a, m1b);
    float m2f = fmaxf(fmaxf(m2a, m2b), fminf(m1a, m1b));
    int idx = up ? i1 : i0;
    bool flg = (m - m2f) < DX;  // exact: final top-2 gap below margin
    float s = s0 + s1, u = u0 + u1;

    float ent = logf(s) - u / s;  // = lse - E[logit]
    float tau = 0.5f - 0.2f * (ent * (1.0f / (7.6246190071f + 1e-8f)));
    float simmax = fmaf(m, TEMPR, 1.0f);  // m is (sim-1)/T
    float dist = sqrtf(fmaxf(2.0f - 2.0f * simmax, 0.0f));
    int grow = row0 + wr * 32 + rowl;
    float g = CONF[idx] / (1.0f + __expf(-(BS[grow] - tau) * INV_T));
    gate_out[grow] = g;
    gd[grow] = g * dist;
    tau_ws[grow] = tau;
    if (flg) {
      pk[grow] = 0ull;  // init merge slot for krescore4
      int p = atomicAdd(cnt, 1);
      flags[p] = grow;
    }
  }
}

// --- kernel 4: fp32 rescore, chunked (16 chunks/row fan out over blocks) ----
// Chunk = 128 protos. Merge via atomicMax on packed (ordered_sim<<32 | NK-idx):
// exact fp32 compare, smaller idx wins ties, order-independent.
__global__ __launch_bounds__(256) void krescore4(
    const float* __restrict__ E, const float* __restrict__ P,
    const float* __restrict__ invp, const int* __restrict__ cnt,
    const int* __restrict__ flags, u64* __restrict__ pk) {
  const int n = *cnt;
  const int total = n * 16;
  const int t = threadIdx.x;
  const int k = t & 15;   // lane in 16-lane group
  const int G = t >> 4;   // group 0..15

  for (int ch = blockIdx.x; ch < total; ch += gridDim.x) {
    const int j = ch >> 4, q = ch & 15;
    const int row = flags[j];
    // E chunk in registers; 16-lane-group shfl norm (same order as round 7)
    float4 e[8];
    float ss = 0.f;
    const float4* er = (const float4*)(E + (size_t)row * ND);
#pragma unroll
    for (int i = 0; i < 8; ++i) {
      e[i] = er[k + 16 * i];
      ss += e[i].x * e[i].x + e[i].y * e[i].y + e[i].z * e[i].z + e[i].w * e[i].w;
    }
#pragma unroll
    for (int o = 1; o < 16; o <<= 1) ss += __shfl_xor(ss, o);
    const float inv = 1.0f / fmaxf(sqrtf(ss), 1e-12f);
#pragma unroll
    for (int i = 0; i < 8; ++i) {
      e[i].x *= inv; e[i].y *= inv; e[i].z *= inv; e[i].w *= inv;
    }

    float best = -3.0e38f;
    int bidx = NK;
#pragma unroll 2
    for (int m = 0; m < 8; ++m) {  // ascending p within group: first-max kept
      const int p = q * 128 + G + 16 * m;
      const float4* pr = (const float4*)(P + (size_t)p * ND);
      float dot = 0.f;
#pragma unroll
      for (int i = 0; i < 8; ++i) {
        float4 a = pr[k + 16 * i];
        dot = fmaf(a.x, e[i].x, dot); dot = fmaf(a.y, e[i].y, dot);
        dot = fmaf(a.z, e[i].z, dot); dot = fmaf(a.w, e[i].w, dot);
      }
#pragma unroll
      for (int o = 1; o < 16; o <<= 1) dot += __shfl_xor(dot, o);
      float sim = dot * invp[p];
      if (sim > best) { best = sim; bidx = p; }
    }
    if (k == 0) {
      unsigned u = __float_as_uint(best);
      unsigned ord = (u & 0x80000000u) ? ~u : (u | 0x80000000u);
      u64 v = ((u64)ord << 32) | (unsigned)(NK - bidx);
      atomicMax(pk + row, v);
    }
  }
}

// ------- kernel 5: flagged-row fixup (unpack pk) + deterministic mean -------
__global__ __launch_bounds__(1024) void kreduce2(
    float* __restrict__ gd, const float* __restrict__ BS,
    const float* __restrict__ CONF, const float* __restrict__ tau_ws,
    const int* __restrict__ cnt, const int* __restrict__ flags,
    const u64* __restrict__ pk, float* __restrict__ out0,
    float* __restrict__ gate_out) {
  __shared__ float red[1024];
  const int t = threadIdx.x;

  // ---- phase 1: fixup flagged rows from packed rescore results ----
  const int n = *cnt;
  for (int j = t; j < n; j += 1024) {
    const int row = flags[j];
    const u64 v = pk[row];
    const unsigned hi = (unsigned)(v >> 32);
    const int idx = NK - (int)(v & 0xFFFFFFFFu);
    const float sim = (hi & 0x80000000u) ? __uint_as_float(hi & 0x7FFFFFFFu)
                                         : __uint_as_float(~hi);
    const float tau = tau_ws[row];
    const float dist = sqrtf(fmaxf(2.0f - 2.0f * sim, 0.0f));
    const float g = CONF[idx] / (1.0f + __expf(-(BS[row] - tau) * INV_T));
    gate_out[row] = g;
    gd[row] = g * dist;
  }
  __syncthreads();  // block-wide visibility of gd fixups

  // ---- phase 2: deterministic mean ----
  float s = 0.f;
  const float4* g4 = (const float4*)gd;
  for (int i = t; i < 8192; i += 1024) {
    float4 v = g4[i];
    s += (v.x + v.y) + (v.z + v.w);
  }
  red[t] = s;
  __syncthreads();
  for (int off = 512; off > 0; off >>= 1) {
    if (t < off) red[t] += red[t + off];
    __syncthreads();
  }
  if (t == 0) out0[0] = red[0] * (1.0f / 32768.0f);
}

extern "C" void kernel_launch(void* const* d_in, const int* in_sizes, int n_in,
                              void* d_out, int out_size, void* d_ws, size_t ws_size,
                              hipStream_t stream) {
  const float* E = (const float*)d_in[0];
  const float* BS = (const float*)d_in[1];
  const float* P = (const float*)d_in[2];
  const float* CONF = (const float*)d_in[3];
  float* out = (float*)d_out;  // [0]=L_proto, [1..32768]=gate

  char* wsb = (char*)d_ws;
  u16* Phi = (u16*)wsb;                                   // 2 MB @ 0 (transposed)
  u16* Plo = (u16*)(wsb + ((size_t)2 << 20));             // 2 MB @ 2M (transposed)
  u16* Ehi = (u16*)(wsb + ((size_t)4 << 20));             // 32 MB @ 4M (row-major)
  u16* Elo = (u16*)(wsb + ((size_t)36 << 20));            // 32 MB @ 36M
  char* tail = wsb + ((size_t)68 << 20);
  float* tau_ws = (float*)tail;                           // 128 KB
  float* gd = (float*)(tail + 131072);                    // 128 KB
  int* flags = (int*)(tail + 2 * 131072);                 // 128 KB
  int* cnt = (int*)(tail + 3 * 131072);                   // 4 KB pad
  float* invp = (float*)(tail + 3 * 131072 + 4096);       // 8 KB
  u64* pk = (u64*)(tail + 3 * 131072 + 4096 + 8192);      // 256 KB

  kprep_p<<<512, 256, 0, stream>>>(P, Phi, Plo, invp, cnt);
  kprep_e2<<<8192, 256, 0, stream>>>(E, Ehi, Elo);
  kmain_v6<<<512, 256, 0, stream>>>(BS, Phi, Plo, Ehi, Elo, CONF, tau_ws, gd,
                                    out + 1, cnt, flags, pk);
  krescore4<<<2048, 256, 0, stream>>>(E, P, invp, cnt, flags, pk);
  kreduce2<<<1, 1024, 0, stream>>>(gd, BS, CONF, tau_ws, cnt, flags, pk,
                                   out, out + 1);
}